// Round 3
// baseline (83.889 us; speedup 1.0000x reference)
//
#include <hip/hip_runtime.h>

// GaussianBasis: 2D gaussian splatting, N=10000 gaussians -> (3,256,256) fp32.
// Tile-GATHER v3 — scan formulation, 2 dispatch nodes, zero global atomics:
//   prep:   per-gaussian params (3 x float4) + PACKED tile-range u32
//           (tx0|tx1<<5|ty0<<10|ty1<<15). No counts, no lists, no memset,
//           no dependence on workspace contents.
//   render: 1024 blocks (one per 8x8 tile) x 256 thr. Each block scans the
//           10000 packed tile-ranges (40 KB, L2-resident, coalesced),
//           compacts matches into an LDS index list (1 LDS atomic per wave
//           via ballot), then stages params into LDS and evaluates with the
//           v2 inner loop (wave-strided j, register RGB accum, cross-wave
//           LDS reduce, fused scale/shift store).

#define IMG_H 256
#define IMG_W 256
#define TILE 8
#define TPX 32          // tiles per axis (256/8)
#define NTILES 1024
#define CAP 512         // max gaussians per tile (worst observed ~150)

__global__ __launch_bounds__(256) void prep_kernel(
    const float* __restrict__ xyz,      // (N,2)
    const float* __restrict__ chol,     // (N,3)
    const float* __restrict__ colors,   // (N,3)
    const float* __restrict__ opacity,  // (N,1)
    int N,
    unsigned int* __restrict__ bbox,    // [N] packed tile ranges
    float4* __restrict__ params)        // [N][3]: (cx,cy,a,b)(c,op,c0,c1)(c2,-,-,-)
{
    const int n = blockIdx.x * 256 + threadIdx.x;
    if (n >= N) return;

    const float mx = tanhf(xyz[2 * n + 0]);
    const float my = tanhf(xyz[2 * n + 1]);
    const float cx = 0.5f * IMG_W * (mx + 1.0f);
    const float cy = 0.5f * IMG_H * (my + 1.0f);

    const float L0 = chol[3 * n + 0] + 0.5f;
    const float L1 = chol[3 * n + 1];
    const float L2 = chol[3 * n + 2] + 0.5f;
    const float cov_xx = L0 * L0;
    const float cov_xy = L0 * L1;
    const float cov_yy = L1 * L1 + L2 * L2;
    const float det = cov_xx * cov_yy - cov_xy * cov_xy;  // = (L0*L2)^2 > 0

    params[3 * n + 0] = make_float4(cx, cy, cov_yy / det, -cov_xy / det);
    params[3 * n + 1] = make_float4(cov_xx / det, opacity[n],
                                    colors[3 * n + 0], colors[3 * n + 1]);
    params[3 * n + 2] = make_float4(colors[3 * n + 2], 0.0f, 0.0f, 0.0f);

    // alpha = op*exp(-sigma) >= 1/255  =>  sigma <= log(255*op) = smax
    const float smax = logf(255.0f * opacity[n]);
    unsigned int packed = 0xFFFFFFFFu;  // sentinel: tx0=31 > tx1=0 -> never matches
    if (smax > 0.0f) {
        const float rx = sqrtf(2.0f * smax * cov_xx) + 1.0f;
        const float ry = sqrtf(2.0f * smax * cov_yy) + 1.0f;
        const int x0 = max(0, (int)floorf(cx - rx));
        const int x1 = min(IMG_W - 1, (int)ceilf(cx + rx));
        const int y0 = max(0, (int)floorf(cy - ry));
        const int y1 = min(IMG_H - 1, (int)ceilf(cy + ry));
        if (x0 <= x1 && y0 <= y1) {
            packed = (unsigned int)(x0 >> 3) | ((unsigned int)(x1 >> 3) << 5) |
                     ((unsigned int)(y0 >> 3) << 10) | ((unsigned int)(y1 >> 3) << 15);
        }
    }
    bbox[n] = packed;
}

__global__ __launch_bounds__(256) void render_kernel(
    const unsigned int* __restrict__ bbox,
    const float4* __restrict__ params,
    const float* __restrict__ scale,
    const float* __restrict__ shift,
    int N,
    float* __restrict__ out)
{
    const int tile = blockIdx.x;
    const int tx = tile & (TPX - 1);
    const int ty = tile >> 5;
    const int wave = threadIdx.x >> 6;   // 0..3
    const int lane = threadIdx.x & 63;
    const int p = lane;                  // pixel within 8x8 tile
    const float px = (float)(tx * TILE + (p & (TILE - 1)));
    const float py = (float)(ty * TILE + (p >> 3));

    __shared__ int lcnt;
    __shared__ int lidx[CAP];
    __shared__ float4 sh[3 * 256];       // 12 KB staged params
    __shared__ float red[3][256];        // 3 KB cross-wave reduction

    if (threadIdx.x == 0) lcnt = 0;
    __syncthreads();

    // --- scan all N packed tile-ranges; compact matches into lidx ---
    const unsigned int txu = (unsigned int)tx;
    const unsigned int tyu = (unsigned int)ty;
    for (int i = threadIdx.x; i < N; i += 256) {
        const unsigned int b = bbox[i];  // coalesced, L2-resident (40 KB total)
        const bool match = ((b & 31u) <= txu) && (txu <= ((b >> 5) & 31u)) &&
                           (((b >> 10) & 31u) <= tyu) && (tyu <= ((b >> 15) & 31u));
        const unsigned long long mask = __ballot(match);
        if (match) {
            const int leader = __ffsll((long long)mask) - 1;
            const int pos = __popcll(mask & ((1ull << lane) - 1ull));
            int basep = 0;
            if (lane == leader) basep = atomicAdd(&lcnt, __popcll(mask));
            basep = __shfl(basep, leader);
            const int slot = basep + pos;
            if (slot < CAP) lidx[slot] = i;
        }
    }
    __syncthreads();
    const int cnt = min(lcnt, CAP);

    float accr = 0.0f, accg = 0.0f, accb = 0.0f;

    for (int base = 0; base < cnt; base += 256) {
        const int m = min(256, cnt - base);
        if (threadIdx.x < m) {
            const int n = lidx[base + threadIdx.x];
            sh[3 * threadIdx.x + 0] = params[3 * n + 0];
            sh[3 * threadIdx.x + 1] = params[3 * n + 1];
            sh[3 * threadIdx.x + 2] = params[3 * n + 2];
        }
        __syncthreads();
        // wave s handles j = s, s+4, ... : uniform j in wave -> LDS broadcast,
        // each list entry evaluated by exactly one wave over all 64 pixels.
        for (int j = wave; j < m; j += 4) {
            const float4 p0 = sh[3 * j + 0];  // cx, cy, a, b
            const float4 p1 = sh[3 * j + 1];  // c, op, col0, col1
            const float c2v = sh[3 * j + 2].x;
            const float dx = p0.x - px;
            const float dy = p0.y - py;
            const float sigma =
                0.5f * (p0.z * dx * dx + p1.x * dy * dy) + p0.w * (dx * dy);
            float alpha = p1.y * __expf(-sigma);
            if (sigma >= 0.0f && alpha >= (1.0f / 255.0f)) {
                alpha = fminf(alpha, 0.999f);
                accr = fmaf(alpha, p1.z, accr);
                accg = fmaf(alpha, p1.w, accg);
                accb = fmaf(alpha, c2v, accb);
            }
        }
        __syncthreads();
    }

    red[0][threadIdx.x] = accr;
    red[1][threadIdx.x] = accg;
    red[2][threadIdx.x] = accb;
    __syncthreads();

    // threads 0..191: c = t>>6, pixel = t&63 ; sum the 4 wave-partials.
    if (threadIdx.x < 192) {
        const int c = threadIdx.x >> 6;
        const int q = threadIdx.x & 63;
        const float sum = red[c][q] + red[c][q + 64] + red[c][q + 128] + red[c][q + 192];
        const int pix = (ty * TILE + (q >> 3)) * IMG_W + tx * TILE + (q & (TILE - 1));
        out[c * IMG_H * IMG_W + pix] = fmaf(sum, scale[0], shift[0]);
    }
}

extern "C" void kernel_launch(void* const* d_in, const int* in_sizes, int n_in,
                              void* d_out, int out_size, void* d_ws, size_t ws_size,
                              hipStream_t stream) {
    const float* xyz     = (const float*)d_in[0];
    const float* chol    = (const float*)d_in[1];
    const float* colors  = (const float*)d_in[2];
    const float* opacity = (const float*)d_in[3];
    const float* scale   = (const float*)d_in[4];
    const float* shift   = (const float*)d_in[5];
    float* out = (float*)d_out;

    const int N = in_sizes[3];  // opacity is (N,1)

    // ws layout: bbox [N u32, padded to 16B] | params [N*3 float4]
    unsigned int* bbox = (unsigned int*)d_ws;
    float4* params = (float4*)((char*)d_ws + ((N * 4 + 15) & ~15));

    prep_kernel<<<(N + 255) / 256, 256, 0, stream>>>(
        xyz, chol, colors, opacity, N, bbox, params);
    render_kernel<<<NTILES, 256, 0, stream>>>(bbox, params, scale, shift, N, out);
}

// Round 4
// 76.940 us; speedup vs baseline: 1.0903x; 1.0903x over previous
//
#include <hip/hip_runtime.h>

// GaussianBasis: 2D gaussian splatting, N=10000 gaussians -> (3,256,256) fp32.
// Tile-GATHER v4 = v2 skeleton (binned lists, best measured) + tail fixes:
//   - prep bins each gaussian's bbox into per-8x8-tile lists; counters padded
//     to one per 64B line (v1 lesson: contention).
//   - render: 1024 blocks x 256 thr; block b renders tile (b*389)&1023 —
//     odd-multiplier bijection scatters the HEAVY BORDER TILES (tanh piles
//     gaussians at image edges; identity mapping put all tx=0 tiles on one
//     XCD since 32 % 8 == 0) across CUs/XCDs.
//   - inner loop: params staged as 2xfloat4 + 1xfloat in LDS (was 3xfloat4),
//     unroll 2 so two j's LDS reads overlap (ds_read latency ~120 cyc).
//   - wave s handles j == s (mod 4): uniform j per wave -> LDS broadcast;
//     cross-wave RGB reduce through LDS; fused scale/shift store.

#define IMG_H 256
#define IMG_W 256
#define TILE 8
#define TPX 32          // tiles per axis (256/8)
#define NTILES 1024
#define CAP 512         // max gaussians per tile list (worst observed ~150)
#define CSTRIDE 16      // counter padding: 16 ints = 64 B line per counter

__global__ __launch_bounds__(64) void prep_bin_kernel(
    const float* __restrict__ xyz,      // (N,2)
    const float* __restrict__ chol,     // (N,3)
    const float* __restrict__ colors,   // (N,3)
    const float* __restrict__ opacity,  // (N,1)
    int N,
    int* __restrict__ counts,           // [NTILES*CSTRIDE]
    int* __restrict__ lists,            // [NTILES][CAP]
    float4* __restrict__ params)        // [N][3]: (cx,cy,a,b)(c,op,c0,c1)(c2,-,-,-)
{
    const int n = blockIdx.x * 64 + threadIdx.x;
    if (n >= N) return;

    const float mx = tanhf(xyz[2 * n + 0]);
    const float my = tanhf(xyz[2 * n + 1]);
    const float cx = 0.5f * IMG_W * (mx + 1.0f);
    const float cy = 0.5f * IMG_H * (my + 1.0f);

    const float L0 = chol[3 * n + 0] + 0.5f;
    const float L1 = chol[3 * n + 1];
    const float L2 = chol[3 * n + 2] + 0.5f;
    const float cov_xx = L0 * L0;
    const float cov_xy = L0 * L1;
    const float cov_yy = L1 * L1 + L2 * L2;
    const float det = cov_xx * cov_yy - cov_xy * cov_xy;  // = (L0*L2)^2 > 0

    const float op = opacity[n];
    params[3 * n + 0] = make_float4(cx, cy, cov_yy / det, -cov_xy / det);
    params[3 * n + 1] = make_float4(cov_xx / det, op,
                                    colors[3 * n + 0], colors[3 * n + 1]);
    params[3 * n + 2] = make_float4(colors[3 * n + 2], 0.0f, 0.0f, 0.0f);

    // alpha = op*exp(-sigma) >= 1/255  =>  sigma <= log(255*op) = smax
    const float smax = logf(255.0f * op);
    if (!(smax > 0.0f)) return;  // never visible

    const float rx = sqrtf(2.0f * smax * cov_xx) + 1.0f;
    const float ry = sqrtf(2.0f * smax * cov_yy) + 1.0f;
    const int x0 = max(0, (int)floorf(cx - rx));
    const int x1 = min(IMG_W - 1, (int)ceilf(cx + rx));
    const int y0 = max(0, (int)floorf(cy - ry));
    const int y1 = min(IMG_H - 1, (int)ceilf(cy + ry));
    if (x0 > x1 || y0 > y1) return;

    const int tx0 = x0 >> 3, tx1 = x1 >> 3;
    const int ty0 = y0 >> 3, ty1 = y1 >> 3;
    for (int ty = ty0; ty <= ty1; ++ty) {
        for (int tx = tx0; tx <= tx1; ++tx) {
            const int t = ty * TPX + tx;
            const int slot = atomicAdd(&counts[t * CSTRIDE], 1);
            if (slot < CAP) lists[t * CAP + slot] = n;
        }
    }
}

__global__ __launch_bounds__(256) void render_kernel(
    const int* __restrict__ counts,
    const int* __restrict__ lists,
    const float4* __restrict__ params,
    const float* __restrict__ scale,
    const float* __restrict__ shift,
    float* __restrict__ out)
{
    // Bijective scatter of tiles over blocks (389 odd => invertible mod 1024):
    // spreads heavy border tiles across CUs and XCDs.
    const int tile = (blockIdx.x * 389) & (NTILES - 1);
    const int tx = tile & (TPX - 1);
    const int ty = tile >> 5;
    const int wave = threadIdx.x >> 6;   // 0..3: gaussian slice
    const int p = threadIdx.x & 63;      // pixel within 8x8 tile
    const float px = (float)(tx * TILE + (p & (TILE - 1)));
    const float py = (float)(ty * TILE + (p >> 3));

    __shared__ float4 sh4[2 * 256];      // (cx,cy,a,b),(c,op,c0,c1) per gaussian
    __shared__ float shc[256];           // c2 per gaussian
    __shared__ float red[3][256];        // cross-wave reduction

    const int cnt = min(counts[tile * CSTRIDE], CAP);
    const int* list = lists + tile * CAP;

    float accr = 0.0f, accg = 0.0f, accb = 0.0f;

    for (int base = 0; base < cnt; base += 256) {
        const int m = min(256, cnt - base);
        __syncthreads();
        if (threadIdx.x < m) {
            const int n = list[base + threadIdx.x];
            sh4[2 * threadIdx.x + 0] = params[3 * n + 0];
            sh4[2 * threadIdx.x + 1] = params[3 * n + 1];
            shc[threadIdx.x] = params[3 * n + 2].x;
        }
        __syncthreads();
        // wave s handles j = s, s+4, ... : uniform j within a wave ->
        // LDS broadcast reads; each list entry touched by exactly one wave.
#pragma unroll 2
        for (int j = wave; j < m; j += 4) {
            const float4 p0 = sh4[2 * j + 0];  // cx, cy, a, b
            const float4 p1 = sh4[2 * j + 1];  // c, op, col0, col1
            const float c2v = shc[j];
            const float dx = p0.x - px;
            const float dy = p0.y - py;
            const float sigma =
                0.5f * (p0.z * dx * dx + p1.x * dy * dy) + p0.w * (dx * dy);
            float alpha = p1.y * __expf(-sigma);
            if (sigma >= 0.0f && alpha >= (1.0f / 255.0f)) {
                alpha = fminf(alpha, 0.999f);
                accr = fmaf(alpha, p1.z, accr);
                accg = fmaf(alpha, p1.w, accg);
                accb = fmaf(alpha, c2v, accb);
            }
        }
    }

    red[0][threadIdx.x] = accr;
    red[1][threadIdx.x] = accg;
    red[2][threadIdx.x] = accb;
    __syncthreads();

    // threads 0..191: c = t>>6, pixel = t&63 ; sum the 4 wave-partials.
    if (threadIdx.x < 192) {
        const int c = threadIdx.x >> 6;
        const int q = threadIdx.x & 63;
        const float sum = red[c][q] + red[c][q + 64] + red[c][q + 128] + red[c][q + 192];
        const int pix = (ty * TILE + (q >> 3)) * IMG_W + tx * TILE + (q & (TILE - 1));
        out[c * IMG_H * IMG_W + pix] = fmaf(sum, scale[0], shift[0]);
    }
}

extern "C" void kernel_launch(void* const* d_in, const int* in_sizes, int n_in,
                              void* d_out, int out_size, void* d_ws, size_t ws_size,
                              hipStream_t stream) {
    const float* xyz     = (const float*)d_in[0];
    const float* chol    = (const float*)d_in[1];
    const float* colors  = (const float*)d_in[2];
    const float* opacity = (const float*)d_in[3];
    const float* scale   = (const float*)d_in[4];
    const float* shift   = (const float*)d_in[5];
    float* out = (float*)d_out;

    const int N = in_sizes[3];  // opacity is (N,1)

    // ws layout: counts [NTILES*CSTRIDE ints = 64 KB] | lists [NTILES*CAP ints = 2 MB]
    //            | params [N*3 float4 = 480 KB]
    int* counts = (int*)d_ws;
    int* lists = counts + NTILES * CSTRIDE;
    float4* params = (float4*)(lists + NTILES * CAP);  // 16B-aligned offset

    hipMemsetAsync(counts, 0, NTILES * CSTRIDE * sizeof(int), stream);
    prep_bin_kernel<<<(N + 63) / 64, 64, 0, stream>>>(
        xyz, chol, colors, opacity, N, counts, lists, params);
    render_kernel<<<NTILES, 256, 0, stream>>>(counts, lists, params, scale, shift, out);
}